// Round 8
// baseline (308.807 us; speedup 1.0000x reference)
//
#include <hip/hip_runtime.h>
#include <hip/hip_bf16.h>
#include <stdint.h>

typedef __attribute__((ext_vector_type(8))) short short8;
typedef __attribute__((ext_vector_type(4))) float f32x4;

#define T_DIM 256
#define NBATCH 64

__device__ __forceinline__ void gload_lds16(const void* g, void* l) {
    __builtin_amdgcn_global_load_lds(
        (const __attribute__((address_space(1))) void*)g,
        (__attribute__((address_space(3))) void*)l, 16, 0, 0);
}

// ---------------- prep: W [(K+1)][O] fp32 -> WT_hi/WT_lo [O][K] bf16 + bias[O] ----
__global__ void prep_w(const float* __restrict__ W, __hip_bfloat16* __restrict__ WTh,
                       __hip_bfloat16* __restrict__ WTl, float* __restrict__ bias,
                       int K, int O) {
    int idx = blockIdx.x * blockDim.x + threadIdx.x;
    int total = O * K;
    if (idx < total) {
        int o = idx / K, i = idx % K;
        float w = W[(size_t)i * O + o];
        __hip_bfloat16 h = __float2bfloat16(w);
        WTh[idx] = h;
        WTl[idx] = __float2bfloat16(w - __bfloat162float(h));
    }
    if (idx < O) bias[idx] = W[(size_t)K * O + idx];
}

// ---------------- prep: x [64][512][256] fp32 -> xh/xl [64][256][512] bf16 --------
__global__ void prep_x(const float* __restrict__ x, __hip_bfloat16* __restrict__ xh,
                       __hip_bfloat16* __restrict__ xl) {
    __shared__ float tile[32][33];
    int b = blockIdx.z;
    int i0 = blockIdx.x * 32;
    int t0 = blockIdx.y * 32;
    int tx = threadIdx.x;
    int ty = threadIdx.y;
    for (int dy = 0; dy < 32; dy += 8)
        tile[ty + dy][tx] = x[((size_t)b * 512 + i0 + ty + dy) * T_DIM + t0 + tx];
    __syncthreads();
    for (int dy = 0; dy < 32; dy += 8) {
        float w = tile[tx][ty + dy];
        size_t dst = ((size_t)b * T_DIM + t0 + ty + dy) * 512 + i0 + tx;
        __hip_bfloat16 h = __float2bfloat16(w);
        xh[dst] = h;
        xl[dst] = __float2bfloat16(w - __bfloat162float(h));
    }
}

// ---------------- hidden-layer GEMM + fused LIF (round-4 K-loop, 128x128 tile) ----
// Tile 128(o) x 128(t), 4 waves (2M x 2N), BK=64, LDS 34KB (K-loop uses 32KB;
// epilogue reuses pool as [64t][132o] fp32 chunk buffer).  Grid = 64b * nOx * 2tt,
// XCD mapping as before.  LIF fused in epilogue with t-tile carry handshake:
//   t-tile 0: scan t=0..127 from acc, write spikes bf16 [b][t][o], write 128 mem
//             carries + agent-scope release flag.
//   t-tile 1: K-loop, then acquire-spin on flag (t0 never waits -> deadlock-free),
//             load carry, scan t=128..255.
// LIF math = identical __fadd_rn(__fmul_rn()) chain on identical fp32 values ->
// bit-identical to the unfused path (absmax canary 2.058594).
__global__ __launch_bounds__(256) void gemm_lif(
    const __hip_bfloat16* __restrict__ A0, const __hip_bfloat16* __restrict__ A1,
    const __hip_bfloat16* __restrict__ A2,
    const __hip_bfloat16* __restrict__ B0, const __hip_bfloat16* __restrict__ B1,
    const __hip_bfloat16* __restrict__ B2,
    const float* __restrict__ bias, __hip_bfloat16* __restrict__ Sout,
    const float* __restrict__ beta_p, const float* __restrict__ thr_p,
    float* __restrict__ carry, int* __restrict__ flags,
    int O, int K, int npass, int nOx) {
    __shared__ __align__(16) char pool[34816];
    __hip_bfloat16* As = (__hip_bfloat16*)pool;            // 128 x 128B = 16KB
    __hip_bfloat16* Bs = (__hip_bfloat16*)(pool + 16384);  // 128 x 128B = 16KB

    const int fid = blockIdx.x;
    const int bpb = nOx * 2;
    const int xcd = fid & 7;
    const int k_in = fid >> 3;
    const int b = xcd * 8 + k_in / bpb;
    const int r_in = k_in % bpb;
    const int o0 = (r_in >> 1) * 128;
    const int tt = r_in & 1;
    const int t0 = tt * 128;

    const int tid = threadIdx.x;
    const int lane = tid & 63;
    const int wave = tid >> 6;
    const int wm = wave >> 1, wn = wave & 1;

    const __hip_bfloat16* Ap[3] = {A0, A1, A2};
    const __hip_bfloat16* Bp[3] = {B0, B1, B2};

    f32x4 acc[4][4] = {};

    const int srow = tid >> 3;         // 0..31
    const int skb  = (tid & 7) * 16;

    for (int p = 0; p < npass; ++p) {
        const __hip_bfloat16* Aptr = Ap[p];
        const __hip_bfloat16* Bptr = Bp[p] + (size_t)b * T_DIM * K;
        for (int k0 = 0; k0 < K; k0 += 64) {
            int src_kb = skb ^ ((srow & 7) << 4);
#pragma unroll
            for (int r = 0; r < 4; ++r) {
                int row = srow + r * 32;
                gload_lds16((const char*)(Aptr + (size_t)(o0 + row) * K + k0) + src_kb,
                            (char*)As + row * 128 + skb);
            }
#pragma unroll
            for (int r = 0; r < 4; ++r) {
                int row = srow + r * 32;
                gload_lds16((const char*)(Bptr + (size_t)(t0 + row) * K + k0) + src_kb,
                            (char*)Bs + row * 128 + skb);
            }
            __syncthreads();
#pragma unroll
            for (int kk = 0; kk < 2; ++kk) {
                short8 af[4], bfr[4];
#pragma unroll
                for (int i = 0; i < 4; ++i) {
                    int row = wm * 64 + i * 16 + (lane & 15);
                    int kb = ((((lane >> 4) * 8) + kk * 32) * 2) ^ ((row & 7) << 4);
                    af[i] = *(const short8*)((const char*)As + row * 128 + kb);
                }
#pragma unroll
                for (int j = 0; j < 4; ++j) {
                    int row = wn * 64 + j * 16 + (lane & 15);
                    int kb = ((((lane >> 4) * 8) + kk * 32) * 2) ^ ((row & 7) << 4);
                    bfr[j] = *(const short8*)((const char*)Bs + row * 128 + kb);
                }
#pragma unroll
                for (int i = 0; i < 4; ++i)
#pragma unroll
                    for (int j = 0; j < 4; ++j)
                        acc[i][j] = __builtin_amdgcn_mfma_f32_16x16x32_bf16(
                            af[i], bfr[j], acc[i][j], 0, 0, 0);
            }
            __syncthreads();
        }
    }

    // ---------------- fused LIF epilogue ----------------
    float sb = 1.f / (1.f + expf(-beta_p[0]));
    float thrv = thr_p[0];
    float* fpool = (float*)pool;          // [64 t][132 o] fp32 = 33792 B
    const int fidx = b * nOx + (o0 >> 7);
    float mem = 0.f;

    if (tt == 1) {
        if (tid == 0) {
            while (__hip_atomic_load(&flags[fidx], __ATOMIC_ACQUIRE,
                                     __HIP_MEMORY_SCOPE_AGENT) == 0)
                __builtin_amdgcn_s_sleep(4);
        }
        __syncthreads();   // flag acquired -> carry visible to all threads
        if (tid < 128) mem = carry[(size_t)b * O + o0 + tid];
    }

    for (int tc = 0; tc < 2; ++tc) {
        __syncthreads();   // pool free (K-loop done / previous chunk consumed)
        if (wn == tc) {
            // dump acc+bias for t-chunk tc: D col(t)=lane&15, row(o)=(lane>>4)*4+r
#pragma unroll
            for (int i = 0; i < 4; ++i) {
                int o = wm * 64 + i * 16 + ((lane >> 4) * 4);
                f32x4 bv = *(const f32x4*)(bias + o0 + o);
#pragma unroll
                for (int j = 0; j < 4; ++j) {
                    int tl = j * 16 + (lane & 15);
                    *(f32x4*)(fpool + tl * 132 + o) = acc[i][j] + bv;
                }
            }
        }
        __syncthreads();
        if (tid < 128) {
#pragma unroll 4
            for (int ttl = 0; ttl < 64; ++ttl) {
                float mu = __fadd_rn(__fmul_rn(sb, mem), fpool[ttl * 132 + tid]);
                float spike = (mu >= thrv) ? 1.f : 0.f;
                mem = mu - spike * thrv;
                Sout[((size_t)b * T_DIM + t0 + tc * 64 + ttl) * O + o0 + tid] =
                    __float2bfloat16(spike);
            }
        }
    }

    if (tt == 0) {
        if (tid < 128) carry[(size_t)b * O + o0 + tid] = mem;
        __syncthreads();   // all carries written before the release
        if (tid == 0)
            __hip_atomic_store(&flags[fidx], 1, __ATOMIC_RELEASE,
                               __HIP_MEMORY_SCOPE_AGENT);
    }
}

// ---------------- 128 x BN GEMM (layer 3) ------------------------------------------
template <int BN>
__global__ __launch_bounds__(256) void gemm_mfma(
    const __hip_bfloat16* __restrict__ A0, const __hip_bfloat16* __restrict__ A1,
    const __hip_bfloat16* __restrict__ A2,
    const __hip_bfloat16* __restrict__ B0, const __hip_bfloat16* __restrict__ B1,
    const __hip_bfloat16* __restrict__ B2,
    const float* __restrict__ bias, float* __restrict__ Cout,
    int O, int K, int npass, int nOx, int nTy) {
    constexpr int NB = BN / 32;
    __shared__ __hip_bfloat16 As[128 * 64];
    __shared__ __hip_bfloat16 Bs[BN * 64];

    const int fid = blockIdx.x;
    const int bpb = nOx * nTy;
    const int xcd = fid & 7;
    const int k_in = fid >> 3;
    const int b = xcd * 8 + k_in / bpb;
    const int r_in = k_in % bpb;
    const int o0 = (r_in / nTy) * 128;
    const int t0 = (r_in % nTy) * BN;

    const int tid = threadIdx.x;
    const int lane = tid & 63;
    const int wave = tid >> 6;
    const int wm = wave >> 1, wn = wave & 1;

    const __hip_bfloat16* Ap[3] = {A0, A1, A2};
    const __hip_bfloat16* Bp[3] = {B0, B1, B2};

    f32x4 acc[4][NB] = {};

    const int srow = tid >> 3;
    const int skb  = (tid & 7) * 16;

    for (int p = 0; p < npass; ++p) {
        const __hip_bfloat16* Aptr = Ap[p];
        const __hip_bfloat16* Bptr = Bp[p] + (size_t)b * T_DIM * K;
        for (int k0 = 0; k0 < K; k0 += 64) {
            int src_kb = skb ^ ((srow & 7) << 4);
#pragma unroll
            for (int r = 0; r < 4; ++r) {
                int row = srow + r * 32;
                gload_lds16((const char*)(Aptr + (size_t)(o0 + row) * K + k0) + src_kb,
                            (char*)As + row * 128 + skb);
            }
#pragma unroll
            for (int r = 0; r < NB; ++r) {
                int row = srow + r * 32;
                gload_lds16((const char*)(Bptr + (size_t)(t0 + row) * K + k0) + src_kb,
                            (char*)Bs + row * 128 + skb);
            }
            __syncthreads();
#pragma unroll
            for (int kk = 0; kk < 2; ++kk) {
                short8 af[4], bfr[NB];
#pragma unroll
                for (int i = 0; i < 4; ++i) {
                    int row = wm * 64 + i * 16 + (lane & 15);
                    int kb = ((((lane >> 4) * 8) + kk * 32) * 2) ^ ((row & 7) << 4);
                    af[i] = *(const short8*)((const char*)As + row * 128 + kb);
                }
#pragma unroll
                for (int j = 0; j < NB; ++j) {
                    int row = wn * (BN / 2) + j * 16 + (lane & 15);
                    int kb = ((((lane >> 4) * 8) + kk * 32) * 2) ^ ((row & 7) << 4);
                    bfr[j] = *(const short8*)((const char*)Bs + row * 128 + kb);
                }
#pragma unroll
                for (int i = 0; i < 4; ++i)
#pragma unroll
                    for (int j = 0; j < NB; ++j)
                        acc[i][j] = __builtin_amdgcn_mfma_f32_16x16x32_bf16(
                            af[i], bfr[j], acc[i][j], 0, 0, 0);
            }
            __syncthreads();
        }
    }
#pragma unroll
    for (int i = 0; i < 4; ++i) {
        int ob = o0 + wm * 64 + i * 16 + ((lane >> 4) * 4);
        f32x4 bv = *(const f32x4*)(bias + ob);
#pragma unroll
        for (int j = 0; j < NB; ++j) {
            int t = t0 + wn * (BN / 2) + j * 16 + (lane & 15);
            f32x4 v = acc[i][j] + bv;
            *(f32x4*)(Cout + ((size_t)b * T_DIM + t) * O + ob) = v;
        }
    }
}

// ---------------- LIF scan: final layer (LDS-transposed coalesced writes) ---------
__global__ __launch_bounds__(64) void lif_final_t(
    const float* __restrict__ pre, float* __restrict__ osp, float* __restrict__ omem,
    const float* __restrict__ beta_p, const float* __restrict__ thr_p) {
    __shared__ float spk[64][33];
    __shared__ float mm[64][33];
    int bid = blockIdx.x;
    int b = bid >> 2, og = bid & 3;
    int lane = threadIdx.x;
    float sb = 1.f / (1.f + expf(-beta_p[0]));
    float thr = thr_p[0];
    float mem = 0.f;
    const float* src = pre + (size_t)b * T_DIM * 256 + og * 64 + lane;
    int bo = b * 256 + og * 64;
    for (int c = 0; c < 8; ++c) {
        int t0 = c * 32;
        float xv[32];
#pragma unroll
        for (int tt = 0; tt < 32; ++tt)
            xv[tt] = src[(size_t)(t0 + tt) * 256];
#pragma unroll
        for (int tt = 0; tt < 32; ++tt) {
            mm[lane][tt] = mem;
            float mu = __fadd_rn(__fmul_rn(sb, mem), xv[tt]);
            float spike = (mu >= thr) ? 1.f : 0.f;
            spk[lane][tt] = spike;
            mem = mu - spike * thr;
        }
#pragma unroll
        for (int it = 0; it < 32; ++it) {
            int row = (lane >> 5) + 2 * it;
            int col = lane & 31;
            size_t dst = ((size_t)bo + row) * T_DIM + t0 + col;
            osp[dst] = spk[row][col];
            omem[dst] = mm[row][col];
        }
    }
}

extern "C" void kernel_launch(void* const* d_in, const int* in_sizes, int n_in,
                              void* d_out, int out_size, void* d_ws, size_t ws_size,
                              hipStream_t stream) {
    const float* x  = (const float*)d_in[0];
    const float* W0 = (const float*)d_in[1];
    const float* W1 = (const float*)d_in[2];
    const float* W2 = (const float*)d_in[3];
    const float* beta = (const float*)d_in[4];
    const float* thr  = (const float*)d_in[5];
    float* out = (float*)d_out;

    char* ws = (char*)d_ws;
    size_t off = 0;
    auto alloc = [&](size_t bytes) {
        size_t r = off;
        off = (off + bytes + 255) & ~(size_t)255;
        return r;
    };
    int*   flags  = (int*)(ws + alloc(1024 * 4));                 // [0:512) L1, [512:1024) L2
    float* carryA = (float*)(ws + alloc((size_t)NBATCH * 1024 * 4));
    float* carryB = (float*)(ws + alloc((size_t)NBATCH * 1024 * 4));
    __hip_bfloat16* w0h = (__hip_bfloat16*)(ws + alloc(1024 * 512 * 2));
    __hip_bfloat16* w0l = (__hip_bfloat16*)(ws + alloc(1024 * 512 * 2));
    float* b0 = (float*)(ws + alloc(1024 * 4));
    __hip_bfloat16* w1h = (__hip_bfloat16*)(ws + alloc(1024 * 1024 * 2));
    __hip_bfloat16* w1l = (__hip_bfloat16*)(ws + alloc(1024 * 1024 * 2));
    float* b1 = (float*)(ws + alloc(1024 * 4));
    __hip_bfloat16* w2h = (__hip_bfloat16*)(ws + alloc(256 * 1024 * 2));
    __hip_bfloat16* w2l = (__hip_bfloat16*)(ws + alloc(256 * 1024 * 2));
    float* b2 = (float*)(ws + alloc(256 * 4));
    __hip_bfloat16* xh = (__hip_bfloat16*)(ws + alloc((size_t)NBATCH * T_DIM * 512 * 2));
    __hip_bfloat16* xl = (__hip_bfloat16*)(ws + alloc((size_t)NBATCH * T_DIM * 512 * 2));
    __hip_bfloat16* S1 = (__hip_bfloat16*)(ws + alloc((size_t)NBATCH * T_DIM * 1024 * 2));
    __hip_bfloat16* S2 = (__hip_bfloat16*)(ws + alloc((size_t)NBATCH * T_DIM * 1024 * 2));
    float* pre = (float*)(ws + alloc((size_t)NBATCH * T_DIM * 256 * 4));
    (void)ws_size; (void)in_sizes; (void)n_in; (void)out_size;

    // zero handshake flags (graph-replay safe: re-runs every launch)
    hipMemsetAsync(flags, 0, 1024 * 4, stream);

    prep_w<<<(1024 * 512 + 255) / 256, 256, 0, stream>>>(W0, w0h, w0l, b0, 512, 1024);
    prep_w<<<(1024 * 1024 + 255) / 256, 256, 0, stream>>>(W1, w1h, w1l, b1, 1024, 1024);
    prep_w<<<(256 * 1024 + 255) / 256, 256, 0, stream>>>(W2, w2h, w2l, b2, 1024, 256);
    prep_x<<<dim3(16, 8, 64), dim3(32, 8), 0, stream>>>(x, xh, xl);

    // Layer 1: O=1024, K=512, 3 planes (xh*Wh + xl*Wh + xh*Wl), fused LIF
    gemm_lif<<<dim3(1024), 256, 0, stream>>>(w0h, w0h, w0l, xh, xl, xh,
                                             b0, S1, beta, thr, carryA, flags,
                                             1024, 512, 3, 8);
    // Layer 2: O=1024, K=1024, 2 planes (S1*Wh + S1*Wl), fused LIF
    gemm_lif<<<dim3(1024), 256, 0, stream>>>(w1h, w1l, w1l, S1, S1, S1,
                                             b1, S2, beta, thr, carryB, flags + 512,
                                             1024, 1024, 2, 8);
    // Layer 3: O=256, K=1024, 2 passes, 128x64 tile -> grid 512
    gemm_mfma<64><<<dim3(512), 256, 0, stream>>>(w2h, w2l, w2l, S2, S2, S2,
                                                 b2, pre, 256, 1024, 2, 2, 4);
    lif_final_t<<<dim3(256), 64, 0, stream>>>(pre, out, out + (size_t)NBATCH * 256 * T_DIM,
                                              beta, thr);
}

// Round 9
// 243.703 us; speedup vs baseline: 1.2671x; 1.2671x over previous
//
#include <hip/hip_runtime.h>
#include <hip/hip_bf16.h>
#include <stdint.h>

typedef __attribute__((ext_vector_type(8))) short short8;
typedef __attribute__((ext_vector_type(4))) float f32x4;

#define T_DIM 256
#define NBATCH 64

__device__ __forceinline__ void gload_lds16(const void* g, void* l) {
    __builtin_amdgcn_global_load_lds(
        (const __attribute__((address_space(1))) void*)g,
        (__attribute__((address_space(3))) void*)l, 16, 0, 0);
}

// ---------------- prep: W [(K+1)][O] fp32 -> WT_hi/WT_lo [O][K] bf16 + bias[O] ----
__global__ void prep_w(const float* __restrict__ W, __hip_bfloat16* __restrict__ WTh,
                       __hip_bfloat16* __restrict__ WTl, float* __restrict__ bias,
                       int K, int O) {
    int idx = blockIdx.x * blockDim.x + threadIdx.x;
    int total = O * K;
    if (idx < total) {
        int o = idx / K, i = idx % K;
        float w = W[(size_t)i * O + o];
        __hip_bfloat16 h = __float2bfloat16(w);
        WTh[idx] = h;
        WTl[idx] = __float2bfloat16(w - __bfloat162float(h));
    }
    if (idx < O) bias[idx] = W[(size_t)K * O + idx];
}

// ---------------- prep: x [64][512][256] fp32 -> xh/xl [64][256][512] bf16 --------
__global__ void prep_x(const float* __restrict__ x, __hip_bfloat16* __restrict__ xh,
                       __hip_bfloat16* __restrict__ xl) {
    __shared__ float tile[32][33];
    int b = blockIdx.z;
    int i0 = blockIdx.x * 32;
    int t0 = blockIdx.y * 32;
    int tx = threadIdx.x;
    int ty = threadIdx.y;
    for (int dy = 0; dy < 32; dy += 8)
        tile[ty + dy][tx] = x[((size_t)b * 512 + i0 + ty + dy) * T_DIM + t0 + tx];
    __syncthreads();
    for (int dy = 0; dy < 32; dy += 8) {
        float w = tile[tx][ty + dy];
        size_t dst = ((size_t)b * T_DIM + t0 + ty + dy) * 512 + i0 + tx;
        __hip_bfloat16 h = __float2bfloat16(w);
        xh[dst] = h;
        xl[dst] = __float2bfloat16(w - __bfloat162float(h));
    }
}

// ---------------- layer-1 GEMM: plane-fused K-sweeps -------------------------------
// pre[b][t][o] = Wh·xh + Wh·xl + Wl·xh + bias.  Tile 128(o)x128(t), 4 waves, BK=64.
// Phase 1: stage {Wh, xh, xl} per k-step (48KB LDS), 64 MFMA/step -> Wh·xh + Wh·xl.
// Phase 2: stage {Wl, xh} per k-step, 32 MFMA/step -> += Wl·xh.
// Same K-loop/sync structure as the proven round-4 kernel; only the inner body
// gains a second B plane.  (Accumulation order interleaves planes per k-tile ->
// last-bit reorder vs round 4; same product set.)
__global__ __launch_bounds__(256) void gemm_l1(
    const __hip_bfloat16* __restrict__ Wh, const __hip_bfloat16* __restrict__ Wl,
    const __hip_bfloat16* __restrict__ xh, const __hip_bfloat16* __restrict__ xl,
    const float* __restrict__ bias, float* __restrict__ Cout, int nOx) {
    const int O = 1024, K = 512;
    __shared__ __hip_bfloat16 As[128 * 64];
    __shared__ __hip_bfloat16 B0s[128 * 64];
    __shared__ __hip_bfloat16 B1s[128 * 64];

    const int fid = blockIdx.x;
    const int bpb = nOx * 2;
    const int xcd = fid & 7;
    const int k_in = fid >> 3;
    const int b = xcd * 8 + k_in / bpb;
    const int r_in = k_in % bpb;
    const int o0 = (r_in >> 1) * 128;
    const int t0 = (r_in & 1) * 128;

    const int tid = threadIdx.x;
    const int lane = tid & 63;
    const int wave = tid >> 6;
    const int wm = wave >> 1, wn = wave & 1;

    f32x4 acc[4][4] = {};

    const int srow = tid >> 3;         // 0..31
    const int skb  = (tid & 7) * 16;
    const int src_kb = skb ^ ((srow & 7) << 4);

    const __hip_bfloat16* xhB = xh + (size_t)b * T_DIM * K;
    const __hip_bfloat16* xlB = xl + (size_t)b * T_DIM * K;

    // ---- phase 1: Wh·xh + Wh·xl ----
    for (int k0 = 0; k0 < K; k0 += 64) {
#pragma unroll
        for (int r = 0; r < 4; ++r) {
            int row = srow + r * 32;
            gload_lds16((const char*)(Wh + (size_t)(o0 + row) * K + k0) + src_kb,
                        (char*)As + row * 128 + skb);
            gload_lds16((const char*)(xhB + (size_t)(t0 + row) * K + k0) + src_kb,
                        (char*)B0s + row * 128 + skb);
            gload_lds16((const char*)(xlB + (size_t)(t0 + row) * K + k0) + src_kb,
                        (char*)B1s + row * 128 + skb);
        }
        __syncthreads();
#pragma unroll
        for (int kk = 0; kk < 2; ++kk) {
            short8 af[4], b0[4], b1[4];
#pragma unroll
            for (int i = 0; i < 4; ++i) {
                int row = wm * 64 + i * 16 + (lane & 15);
                int kb = ((((lane >> 4) * 8) + kk * 32) * 2) ^ ((row & 7) << 4);
                af[i] = *(const short8*)((const char*)As + row * 128 + kb);
            }
#pragma unroll
            for (int j = 0; j < 4; ++j) {
                int row = wn * 64 + j * 16 + (lane & 15);
                int kb = ((((lane >> 4) * 8) + kk * 32) * 2) ^ ((row & 7) << 4);
                b0[j] = *(const short8*)((const char*)B0s + row * 128 + kb);
                b1[j] = *(const short8*)((const char*)B1s + row * 128 + kb);
            }
#pragma unroll
            for (int i = 0; i < 4; ++i)
#pragma unroll
                for (int j = 0; j < 4; ++j)
                    acc[i][j] = __builtin_amdgcn_mfma_f32_16x16x32_bf16(
                        af[i], b0[j], acc[i][j], 0, 0, 0);
#pragma unroll
            for (int i = 0; i < 4; ++i)
#pragma unroll
                for (int j = 0; j < 4; ++j)
                    acc[i][j] = __builtin_amdgcn_mfma_f32_16x16x32_bf16(
                        af[i], b1[j], acc[i][j], 0, 0, 0);
        }
        __syncthreads();
    }

    // ---- phase 2: += Wl·xh ----
    for (int k0 = 0; k0 < K; k0 += 64) {
#pragma unroll
        for (int r = 0; r < 4; ++r) {
            int row = srow + r * 32;
            gload_lds16((const char*)(Wl + (size_t)(o0 + row) * K + k0) + src_kb,
                        (char*)As + row * 128 + skb);
            gload_lds16((const char*)(xhB + (size_t)(t0 + row) * K + k0) + src_kb,
                        (char*)B0s + row * 128 + skb);
        }
        __syncthreads();
#pragma unroll
        for (int kk = 0; kk < 2; ++kk) {
            short8 af[4], b0[4];
#pragma unroll
            for (int i = 0; i < 4; ++i) {
                int row = wm * 64 + i * 16 + (lane & 15);
                int kb = ((((lane >> 4) * 8) + kk * 32) * 2) ^ ((row & 7) << 4);
                af[i] = *(const short8*)((const char*)As + row * 128 + kb);
            }
#pragma unroll
            for (int j = 0; j < 4; ++j) {
                int row = wn * 64 + j * 16 + (lane & 15);
                int kb = ((((lane >> 4) * 8) + kk * 32) * 2) ^ ((row & 7) << 4);
                b0[j] = *(const short8*)((const char*)B0s + row * 128 + kb);
            }
#pragma unroll
            for (int i = 0; i < 4; ++i)
#pragma unroll
                for (int j = 0; j < 4; ++j)
                    acc[i][j] = __builtin_amdgcn_mfma_f32_16x16x32_bf16(
                        af[i], b0[j], acc[i][j], 0, 0, 0);
        }
        __syncthreads();
    }

    // epilogue: D col(t)=lane&15, row(o)=(lane>>4)*4+r -> float4/lane into [b][t][o]
#pragma unroll
    for (int i = 0; i < 4; ++i) {
        int ob = o0 + wm * 64 + i * 16 + ((lane >> 4) * 4);
        f32x4 bv = *(const f32x4*)(bias + ob);
#pragma unroll
        for (int j = 0; j < 4; ++j) {
            int t = t0 + wn * 64 + j * 16 + (lane & 15);
            *(f32x4*)(Cout + ((size_t)b * T_DIM + t) * O + ob) = acc[i][j] + bv;
        }
    }
}

// ---------------- layers 2/3 GEMM: two A planes share one staged B ----------------
// pre[b][t][o] = Ah[o][:]·B[b][t][:] + Al[o][:]·B[b][t][:] + bias[o].
// Per k-step stage {Ah, Al, B} (B fetched ONCE), 64 MFMA/step.
template <int BN>
__global__ __launch_bounds__(256) void gemm_2a1b(
    const __hip_bfloat16* __restrict__ Ah, const __hip_bfloat16* __restrict__ Al,
    const __hip_bfloat16* __restrict__ B,
    const float* __restrict__ bias, float* __restrict__ Cout,
    int O, int K, int nOx, int nTy) {
    constexpr int NB = BN / 32;
    __shared__ __hip_bfloat16 Ash[128 * 64];
    __shared__ __hip_bfloat16 Asl[128 * 64];
    __shared__ __hip_bfloat16 Bs[BN * 64];

    const int fid = blockIdx.x;
    const int bpb = nOx * nTy;
    const int xcd = fid & 7;
    const int k_in = fid >> 3;
    const int b = xcd * 8 + k_in / bpb;
    const int r_in = k_in % bpb;
    const int o0 = (r_in / nTy) * 128;
    const int t0 = (r_in % nTy) * BN;

    const int tid = threadIdx.x;
    const int lane = tid & 63;
    const int wave = tid >> 6;
    const int wm = wave >> 1, wn = wave & 1;

    f32x4 acc[4][NB] = {};

    const int srow = tid >> 3;
    const int skb  = (tid & 7) * 16;
    const int src_kb = skb ^ ((srow & 7) << 4);

    const __hip_bfloat16* Bb = B + (size_t)b * T_DIM * K;

    for (int k0 = 0; k0 < K; k0 += 64) {
#pragma unroll
        for (int r = 0; r < 4; ++r) {
            int row = srow + r * 32;
            gload_lds16((const char*)(Ah + (size_t)(o0 + row) * K + k0) + src_kb,
                        (char*)Ash + row * 128 + skb);
            gload_lds16((const char*)(Al + (size_t)(o0 + row) * K + k0) + src_kb,
                        (char*)Asl + row * 128 + skb);
        }
#pragma unroll
        for (int r = 0; r < NB; ++r) {
            int row = srow + r * 32;
            gload_lds16((const char*)(Bb + (size_t)(t0 + row) * K + k0) + src_kb,
                        (char*)Bs + row * 128 + skb);
        }
        __syncthreads();
#pragma unroll
        for (int kk = 0; kk < 2; ++kk) {
            short8 afh[4], afl[4], bfr[NB];
#pragma unroll
            for (int i = 0; i < 4; ++i) {
                int row = wm * 64 + i * 16 + (lane & 15);
                int kb = ((((lane >> 4) * 8) + kk * 32) * 2) ^ ((row & 7) << 4);
                afh[i] = *(const short8*)((const char*)Ash + row * 128 + kb);
                afl[i] = *(const short8*)((const char*)Asl + row * 128 + kb);
            }
#pragma unroll
            for (int j = 0; j < NB; ++j) {
                int row = wn * (BN / 2) + j * 16 + (lane & 15);
                int kb = ((((lane >> 4) * 8) + kk * 32) * 2) ^ ((row & 7) << 4);
                bfr[j] = *(const short8*)((const char*)Bs + row * 128 + kb);
            }
#pragma unroll
            for (int i = 0; i < 4; ++i)
#pragma unroll
                for (int j = 0; j < NB; ++j)
                    acc[i][j] = __builtin_amdgcn_mfma_f32_16x16x32_bf16(
                        afh[i], bfr[j], acc[i][j], 0, 0, 0);
#pragma unroll
            for (int i = 0; i < 4; ++i)
#pragma unroll
                for (int j = 0; j < NB; ++j)
                    acc[i][j] = __builtin_amdgcn_mfma_f32_16x16x32_bf16(
                        afl[i], bfr[j], acc[i][j], 0, 0, 0);
        }
        __syncthreads();
    }
#pragma unroll
    for (int i = 0; i < 4; ++i) {
        int ob = o0 + wm * 64 + i * 16 + ((lane >> 4) * 4);
        f32x4 bv = *(const f32x4*)(bias + ob);
#pragma unroll
        for (int j = 0; j < NB; ++j) {
            int t = t0 + wn * (BN / 2) + j * 16 + (lane & 15);
            f32x4 v = acc[i][j] + bv;
            *(f32x4*)(Cout + ((size_t)b * T_DIM + t) * O + ob) = v;
        }
    }
}

// ---------------- LIF scan: hidden layers (thread per neuron, coalesced) ----------
__global__ void lif_hidden(const float* __restrict__ pre, __hip_bfloat16* __restrict__ st,
                           const float* __restrict__ beta_p, const float* __restrict__ thr_p,
                           int O) {
    int idx = blockIdx.x * blockDim.x + threadIdx.x;
    int b = idx / O, o = idx - b * O;
    float sb = 1.f / (1.f + expf(-beta_p[0]));
    float thr = thr_p[0];
    float mem = 0.f;
    const float* src = pre + (size_t)b * T_DIM * O + o;
    __hip_bfloat16* dst = st + (size_t)b * T_DIM * O + o;
    for (int t = 0; t < T_DIM; ++t) {
        float mu = __fadd_rn(__fmul_rn(sb, mem), src[(size_t)t * O]);
        float spike = (mu >= thr) ? 1.f : 0.f;
        mem = mu - spike * thr;
        dst[(size_t)t * O] = __float2bfloat16(spike);
    }
}

// ---------------- LIF scan: final layer (LDS-transposed coalesced writes) ---------
__global__ __launch_bounds__(64) void lif_final_t(
    const float* __restrict__ pre, float* __restrict__ osp, float* __restrict__ omem,
    const float* __restrict__ beta_p, const float* __restrict__ thr_p) {
    __shared__ float spk[64][33];
    __shared__ float mm[64][33];
    int bid = blockIdx.x;
    int b = bid >> 2, og = bid & 3;
    int lane = threadIdx.x;
    float sb = 1.f / (1.f + expf(-beta_p[0]));
    float thr = thr_p[0];
    float mem = 0.f;
    const float* src = pre + (size_t)b * T_DIM * 256 + og * 64 + lane;
    int bo = b * 256 + og * 64;
    for (int c = 0; c < 8; ++c) {
        int t0 = c * 32;
        float xv[32];
#pragma unroll
        for (int tt = 0; tt < 32; ++tt)
            xv[tt] = src[(size_t)(t0 + tt) * 256];
#pragma unroll
        for (int tt = 0; tt < 32; ++tt) {
            mm[lane][tt] = mem;
            float mu = __fadd_rn(__fmul_rn(sb, mem), xv[tt]);
            float spike = (mu >= thr) ? 1.f : 0.f;
            spk[lane][tt] = spike;
            mem = mu - spike * thr;
        }
#pragma unroll
        for (int it = 0; it < 32; ++it) {
            int row = (lane >> 5) + 2 * it;
            int col = lane & 31;
            size_t dst = ((size_t)bo + row) * T_DIM + t0 + col;
            osp[dst] = spk[row][col];
            omem[dst] = mm[row][col];
        }
    }
}

extern "C" void kernel_launch(void* const* d_in, const int* in_sizes, int n_in,
                              void* d_out, int out_size, void* d_ws, size_t ws_size,
                              hipStream_t stream) {
    const float* x  = (const float*)d_in[0];
    const float* W0 = (const float*)d_in[1];
    const float* W1 = (const float*)d_in[2];
    const float* W2 = (const float*)d_in[3];
    const float* beta = (const float*)d_in[4];
    const float* thr  = (const float*)d_in[5];
    float* out = (float*)d_out;

    char* ws = (char*)d_ws;
    size_t off = 0;
    auto alloc = [&](size_t bytes) {
        size_t r = off;
        off = (off + bytes + 255) & ~(size_t)255;
        return r;
    };
    __hip_bfloat16* w0h = (__hip_bfloat16*)(ws + alloc(1024 * 512 * 2));
    __hip_bfloat16* w0l = (__hip_bfloat16*)(ws + alloc(1024 * 512 * 2));
    float* b0 = (float*)(ws + alloc(1024 * 4));
    __hip_bfloat16* w1h = (__hip_bfloat16*)(ws + alloc(1024 * 1024 * 2));
    __hip_bfloat16* w1l = (__hip_bfloat16*)(ws + alloc(1024 * 1024 * 2));
    float* b1 = (float*)(ws + alloc(1024 * 4));
    __hip_bfloat16* w2h = (__hip_bfloat16*)(ws + alloc(256 * 1024 * 2));
    __hip_bfloat16* w2l = (__hip_bfloat16*)(ws + alloc(256 * 1024 * 2));
    float* b2 = (float*)(ws + alloc(256 * 4));
    __hip_bfloat16* xh = (__hip_bfloat16*)(ws + alloc((size_t)NBATCH * T_DIM * 512 * 2));
    __hip_bfloat16* xl = (__hip_bfloat16*)(ws + alloc((size_t)NBATCH * T_DIM * 512 * 2));
    __hip_bfloat16* S  = (__hip_bfloat16*)(ws + alloc((size_t)NBATCH * T_DIM * 1024 * 2));
    float* pre = (float*)(ws + alloc((size_t)NBATCH * T_DIM * 1024 * 4));
    (void)ws_size; (void)in_sizes; (void)n_in; (void)out_size;

    prep_w<<<(1024 * 512 + 255) / 256, 256, 0, stream>>>(W0, w0h, w0l, b0, 512, 1024);
    prep_w<<<(1024 * 1024 + 255) / 256, 256, 0, stream>>>(W1, w1h, w1l, b1, 1024, 1024);
    prep_w<<<(256 * 1024 + 255) / 256, 256, 0, stream>>>(W2, w2h, w2l, b2, 1024, 256);
    prep_x<<<dim3(16, 8, 64), dim3(32, 8), 0, stream>>>(x, xh, xl);

    // Layer 1: plane-fused (Wh·xh + Wh·xl) + (Wl·xh); grid = 64*8*2
    gemm_l1<<<dim3(1024), 256, 0, stream>>>(w0h, w0l, xh, xl, b0, pre, 8);
    lif_hidden<<<(NBATCH * 1024) / 256, 256, 0, stream>>>(pre, S, beta, thr, 1024);

    // Layer 2: O=1024, K=1024, S staged once per k-step
    gemm_2a1b<128><<<dim3(1024), 256, 0, stream>>>(w1h, w1l, S, b1, pre, 1024, 1024, 8, 2);
    lif_hidden<<<(NBATCH * 1024) / 256, 256, 0, stream>>>(pre, S, beta, thr, 1024);

    // Layer 3: O=256, K=1024, BN=64 -> grid 512
    gemm_2a1b<64><<<dim3(512), 256, 0, stream>>>(w2h, w2l, S, b2, pre, 256, 1024, 2, 4);
    lif_final_t<<<dim3(256), 64, 0, stream>>>(pre, out, out + (size_t)NBATCH * 256 * T_DIM,
                                              beta, thr);
}